// Round 3
// baseline (5929.225 us; speedup 1.0000x reference)
//
#include <hip/hip_runtime.h>
#include <hip/hip_bf16.h>

#define NT 50
#define NB 512
#define SD 256
#define AD 32
#define BD 1024
#define HD 1024
#define ED 1024
#define MD 256

typedef __attribute__((ext_vector_type(8))) short bf16x8;
typedef __attribute__((ext_vector_type(4))) float f32x4;

__device__ __forceinline__ void gload_lds16(const void* g, void* l) {
  __builtin_amdgcn_global_load_lds(
      (const __attribute__((address_space(1))) void*)g,
      (__attribute__((address_space(3))) void*)l, 16, 0, 0);
}

__device__ __forceinline__ float sigmoidf_(float x) { return 1.0f / (1.0f + __expf(-x)); }
__device__ __forceinline__ float softplusf_(float x) {
  return (x > 0.0f) ? (x + log1pf(__expf(-x))) : log1pf(__expf(x));
}

// -------- unified GEMM descriptor --------
struct GD {
  const __hip_bfloat16* A1; const __hip_bfloat16* A2;  // A2 covers K-range [K1, K)
  int lda1, lda2, K1, K;
  const __hip_bfloat16* W; int ldw;
  const float* bias;
  float* Cf; __hip_bfloat16* Cb; int ldc;              // EPI 0/1
  const float* noise; float* st_o; float* mn_o; float* sd_o;  // EPI 2
  const float* ntn; __hip_bfloat16* sprev; int isq;           // EPI 2
};

#define WAITB(N)                                           \
  asm volatile("s_waitcnt vmcnt(" #N ")" ::: "memory");    \
  __builtin_amdgcn_s_barrier();                            \
  __builtin_amdgcn_sched_barrier(0);

// -------- pipelined GEMM: C = epi(A @ W^T + bias) --------
// Tile BM=64 x BN=128, 4 waves (2 row x 2 col), wave = 32x64 (2x4 frags of 16x16),
// BK=32. 4 LDS buffers (12KB each), depth-3 prefetch, counted vmcnt (3 loads/stage).
// LDS 16B-chunk layout per buffer: A [kc(4)][row(64)], B [kc(4)][col(128)] --
// linear in global_load_lds lane order AND conflict-free on ds_read_b128.
// EPI: 0 = fp32 out, 1 = relu->bf16 out, 2 = head epilogue (mean/raw interleaved).
template <int EPI>
__global__ __launch_bounds__(256) void gemm_p(GD d0, GD d1) {
  __shared__ alignas(16) char lds[4 * 12288];  // 48 KiB

  // XCD-aware panel swizzle: all 8 m-tiles of one (n-panel, z) land on one XCD.
  const int NY = gridDim.y;
  const int tot = NY * gridDim.z;                 // panels total (multiple of 8)
  const int l = blockIdx.x + (blockIdx.y + blockIdx.z * NY) * 8;
  const int ppx = tot >> 3;
  const int q = l >> 3;
  const int pan = (l & 7) * ppx + (q >> 3);
  const int m0 = (q & 7) * 64;
  const int n0 = (pan % NY) * 128;
  const GD d = ((pan / NY) == 0) ? d0 : d1;

  const int tid = threadIdx.x;
  const int lane = tid & 63;
  const int w = tid >> 6;
  const int wr = w >> 1, wc = w & 1;

  f32x4 acc[2][4] = {};

  const __hip_bfloat16* a1row = d.A1 + (size_t)(m0 + lane) * d.lda1;
  const __hip_bfloat16* a2row = d.A2 ? d.A2 + (size_t)(m0 + lane) * d.lda2 : nullptr;
  const __hip_bfloat16* wrow0 = d.W + (size_t)(n0 + (w & 1) * 64 + lane) * d.ldw;

  auto stage = [&](int buf, int k0) {
    char* la = lds + (size_t)buf * 12288;
    char* lb = la + 4096;
    const __hip_bfloat16* as = (k0 < d.K1) ? (a1row + k0) : (a2row + (k0 - d.K1));
    gload_lds16(as + w * 8, la + w * 1024);                         // A: kc=w, row=lane
    gload_lds16(wrow0 + k0 + (w >> 1) * 8, lb + w * 1024);          // B r=0
    gload_lds16(wrow0 + k0 + (2 + (w >> 1)) * 8, lb + 4096 + w * 1024);  // B r=1
  };

  const int kc = lane >> 4, r15 = lane & 15;
  auto compute = [&](int i) {
    const char* la = lds + (size_t)(i & 3) * 12288;
    const char* lb = la + 4096;
    bf16x8 af[2], bfr[4];
#pragma unroll
    for (int m = 0; m < 2; ++m)
      af[m] = *(const bf16x8*)(la + (size_t)(kc * 64 + wr * 32 + m * 16 + r15) * 16);
#pragma unroll
    for (int n = 0; n < 4; ++n)
      bfr[n] = *(const bf16x8*)(lb + (size_t)(kc * 128 + wc * 64 + n * 16 + r15) * 16);
#pragma unroll
    for (int m = 0; m < 2; ++m)
#pragma unroll
      for (int n = 0; n < 4; ++n)
        acc[m][n] = __builtin_amdgcn_mfma_f32_16x16x32_bf16(af[m], bfr[n], acc[m][n], 0, 0, 0);
  };

  const int n_it = d.K >> 5;   // >= 17 for all call sites
  stage(0, 0);
  stage(1, 32);
  stage(2, 64);
  int i = 0;
  for (; i < n_it - 2; ++i) {
    WAITB(6)
    if (i < n_it - 3) stage((i + 3) & 3, (i + 3) << 5);
    compute(i);
  }
  WAITB(3)
  compute(i);
  ++i;
  WAITB(0)
  compute(i);

  const int rg = lane >> 4;
  if (EPI == 2) {
    const bool even = (r15 & 1) == 0;
#pragma unroll
    for (int m = 0; m < 2; ++m) {
#pragma unroll
      for (int n = 0; n < 4; ++n) {
        const int col = n0 + wc * 64 + n * 16 + r15;  // interleaved mean/raw
        const int j = col >> 1;
        const float bv = d.bias[col];
#pragma unroll
        for (int ii = 0; ii < 4; ++ii) {
          const int row = m0 + wr * 32 + m * 16 + rg * 4 + ii;
          float v = acc[m][n][ii] + bv;
          float partner = __shfl_xor(v, 1);
          float mean = even ? v : partner;
          float raw = even ? partner : v;
          float sd = fminf(softplusf_(raw) + 0.1f, 5.0f);
          const size_t o = (size_t)row * SD + j;
          if (even) {
            float st = mean + sd * d.noise[o];
            d.mn_o[o] = mean;
            d.st_o[o] = st;
            if (d.isq) d.sprev[o] = __float2bfloat16(st * d.ntn[row]);
          } else {
            d.sd_o[o] = sd;
          }
        }
      }
    }
  } else {
#pragma unroll
    for (int m = 0; m < 2; ++m) {
#pragma unroll
      for (int n = 0; n < 4; ++n) {
        const int col = n0 + wc * 64 + n * 16 + r15;
        const float bv = d.bias[col];
#pragma unroll
        for (int ii = 0; ii < 4; ++ii) {
          const int row = m0 + wr * 32 + m * 16 + rg * 4 + ii;
          float v = acc[m][n][ii] + bv;
          if (EPI == 1) {
            v = v > 0.0f ? v : 0.0f;
            d.Cb[(size_t)row * d.ldc + col] = __float2bfloat16(v);
          } else {
            d.Cf[(size_t)row * d.ldc + col] = v;
          }
        }
      }
    }
  }
}

// ---------------- pointwise / prep kernels ----------------

__global__ void cvt_f32_bf16(const float* __restrict__ src, __hip_bfloat16* __restrict__ dst, int n) {
  int i = blockIdx.x * 256 + threadIdx.x;
  if (i < n) dst[i] = __float2bfloat16(src[i]);
}

// reorder W (512 x 1024): src row j<256 -> dst row 2j (mean), j>=256 -> 2(j-256)+1 (raw)
__global__ void cvt_reorder_w(const float* __restrict__ src, __hip_bfloat16* __restrict__ dst) {
  int i = blockIdx.x * 256 + threadIdx.x;
  if (i >= 512 * 1024) return;
  int r = i >> 10, k = i & 1023;
  int dr = (r < 256) ? (2 * r) : (2 * (r - 256) + 1);
  dst[(size_t)dr * 1024 + k] = __float2bfloat16(src[i]);
}

__global__ void reorder_bias(const float* __restrict__ src, float* __restrict__ dst) {
  int i = blockIdx.x * 256 + threadIdx.x;
  if (i >= 512) return;
  int dr = (i < 256) ? (2 * i) : (2 * (i - 256) + 1);
  dst[dr] = src[i];
}

// actme_b[t][b][0:288] = [act | me] bf16
__global__ void build_actme(const float* __restrict__ act, const float* __restrict__ me,
                            __hip_bfloat16* __restrict__ dst) {
  int i = blockIdx.x * 256 + threadIdx.x;
  if (i >= NT * NB * 288) return;
  int tb = i / 288, j = i - tb * 288;
  float v = (j < AD) ? act[(size_t)tb * AD + j] : me[(size_t)tb * MD + (j - AD)];
  dst[i] = __float2bfloat16(v);
}

// t=0 init: sprev_b = bf16(prev_state*nt0), bel_b = bf16(prev_belief)
__global__ void init_state(const float* __restrict__ prev_state, const float* __restrict__ nt0,
                           const float* __restrict__ prev_belief,
                           __hip_bfloat16* __restrict__ sprev_b, __hip_bfloat16* __restrict__ bel_b) {
  int i = blockIdx.x * 256 + threadIdx.x;
  if (i >= NB * 1280) return;
  int b = i / 1280, j = i - b * 1280;
  if (j < SD) sprev_b[b * SD + j] = __float2bfloat16(prev_state[b * SD + j] * nt0[b]);
  else bel_b[(size_t)b * BD + (j - SD)] = __float2bfloat16(prev_belief[(size_t)b * BD + (j - SD)]);
}

// GRU pointwise + obs/mp bf16 build (independent halves, one dispatch)
__global__ void gru_obs(const float* __restrict__ gi, const float* __restrict__ gh,
                        const float* __restrict__ hprev,
                        const float* __restrict__ obs_t, const float* __restrict__ mp_t,
                        float* __restrict__ bel_out, __hip_bfloat16* __restrict__ bel_b,
                        __hip_bfloat16* __restrict__ obsmp_b) {
  int i = blockIdx.x * 256 + threadIdx.x;
  if (i >= NB * 2304) return;
  int b = i / 2304, j = i - b * 2304;
  if (j < BD) {
    const float* gib = gi + (size_t)b * 3072;
    const float* ghb = gh + (size_t)b * 3072;
    float r = sigmoidf_(gib[j] + ghb[j]);
    float z = sigmoidf_(gib[j + 1024] + ghb[j + 1024]);
    float n = tanhf(gib[j + 2048] + r * ghb[j + 2048]);
    float hv = hprev[(size_t)b * BD + j];
    float bel = (1.0f - z) * n + z * hv;
    bel_out[(size_t)b * BD + j] = bel;
    bel_b[(size_t)b * BD + j] = __float2bfloat16(bel);
  } else {
    int jj = j - BD;
    float v = (jj < ED) ? obs_t[(size_t)b * ED + jj] : mp_t[(size_t)b * MD + (jj - ED)];
    obsmp_b[(size_t)b * 1280 + jj] = __float2bfloat16(v);
  }
}

// ---------------- host ----------------

extern "C" void kernel_launch(void* const* d_in, const int* in_sizes, int n_in,
                              void* d_out, int out_size, void* d_ws, size_t ws_size,
                              hipStream_t stream) {
  const float* prev_state   = (const float*)d_in[0];
  const float* actions      = (const float*)d_in[1];
  const float* prev_belief  = (const float*)d_in[2];
  const float* observations = (const float*)d_in[3];
  const float* nonterminals = (const float*)d_in[4];
  const float* me           = (const float*)d_in[5];
  const float* mp           = (const float*)d_in[6];
  const float* noise_p      = (const float*)d_in[7];
  const float* noise_q      = (const float*)d_in[8];
  const float* W_sa = (const float*)d_in[9];  const float* b_sa = (const float*)d_in[10];
  const float* W_ih = (const float*)d_in[11]; const float* b_ih = (const float*)d_in[12];
  const float* W_hh = (const float*)d_in[13]; const float* b_hh = (const float*)d_in[14];
  const float* W_bp = (const float*)d_in[15]; const float* b_bp = (const float*)d_in[16];
  const float* W_sp = (const float*)d_in[17]; const float* b_sp = (const float*)d_in[18];
  const float* W_bq = (const float*)d_in[19]; const float* b_bq = (const float*)d_in[20];
  const float* W_sq = (const float*)d_in[21]; const float* b_sq = (const float*)d_in[22];
  float* out = (float*)d_out;

  char* p = (char*)d_ws;
  auto carve = [&](size_t bytes) -> char* {
    char* r = p;
    p += (bytes + 255) & ~(size_t)255;
    return r;
  };
  __hip_bfloat16* Wsa_b  = (__hip_bfloat16*)carve((size_t)BD * 544 * 2);
  __hip_bfloat16* Wih_b  = (__hip_bfloat16*)carve((size_t)3 * BD * BD * 2);
  __hip_bfloat16* Whh_b  = (__hip_bfloat16*)carve((size_t)3 * BD * BD * 2);
  __hip_bfloat16* Wbp_b  = (__hip_bfloat16*)carve((size_t)HD * BD * 2);
  __hip_bfloat16* Wsp_ro = (__hip_bfloat16*)carve((size_t)512 * HD * 2);
  __hip_bfloat16* Wbq_b  = (__hip_bfloat16*)carve((size_t)HD * 2304 * 2);
  __hip_bfloat16* Wsq_ro = (__hip_bfloat16*)carve((size_t)512 * HD * 2);
  float* bsp_ro = (float*)carve(512 * 4);
  float* bsq_ro = (float*)carve(512 * 4);
  __hip_bfloat16* actme_b = (__hip_bfloat16*)carve((size_t)NT * NB * 288 * 2);
  __hip_bfloat16* obsmp_b = (__hip_bfloat16*)carve((size_t)NB * 1280 * 2);
  __hip_bfloat16* sprev_b = (__hip_bfloat16*)carve((size_t)NB * SD * 2);
  __hip_bfloat16* bel_b   = (__hip_bfloat16*)carve((size_t)NB * BD * 2);
  __hip_bfloat16* hid_b   = (__hip_bfloat16*)carve((size_t)NB * BD * 2);
  __hip_bfloat16* hp_b    = (__hip_bfloat16*)carve((size_t)NB * HD * 2);
  __hip_bfloat16* hq_b    = (__hip_bfloat16*)carve((size_t)NB * HD * 2);
  float* gi_f = (float*)carve((size_t)NB * 3 * BD * 4);
  float* gh_f = (float*)carve((size_t)NB * 3 * BD * 4);

  auto cvt = [&](const float* s, __hip_bfloat16* d, int n) {
    cvt_f32_bf16<<<(n + 255) / 256, 256, 0, stream>>>(s, d, n);
  };
  cvt(W_sa, Wsa_b, BD * 544);
  cvt(W_ih, Wih_b, 3 * BD * BD);
  cvt(W_hh, Whh_b, 3 * BD * BD);
  cvt(W_bp, Wbp_b, HD * BD);
  cvt(W_bq, Wbq_b, HD * 2304);
  cvt_reorder_w<<<(512 * 1024 + 255) / 256, 256, 0, stream>>>(W_sp, Wsp_ro);
  cvt_reorder_w<<<(512 * 1024 + 255) / 256, 256, 0, stream>>>(W_sq, Wsq_ro);
  reorder_bias<<<2, 256, 0, stream>>>(b_sp, bsp_ro);
  reorder_bias<<<2, 256, 0, stream>>>(b_sq, bsq_ro);
  build_actme<<<(NT * NB * 288 + 255) / 256, 256, 0, stream>>>(actions, me, actme_b);
  init_state<<<(NB * 1280 + 255) / 256, 256, 0, stream>>>(prev_state, nonterminals,
                                                          prev_belief, sprev_b, bel_b);

  const size_t o_ps = (size_t)NT * NB * BD;
  const size_t blk  = (size_t)NT * NB * SD;

  GD z{};  // zero template

  for (int t = 0; t < NT; ++t) {
    const float* obs_t = observations + (size_t)t * NB * ED;
    const float* mp_t  = mp + (size_t)t * NB * MD;
    const float* np_t  = noise_p + (size_t)t * NB * SD;
    const float* nq_t  = noise_q + (size_t)t * NB * SD;
    float* out_bel = out + (size_t)t * NB * BD;
    const float* hprev = (t == 0) ? prev_belief : (out + (size_t)(t - 1) * NB * BD);
    const float* ntn = nonterminals + (size_t)((t + 1 < NT) ? t + 1 : t) * NB;

    // 1) hid = relu([sprev | actme_t] @ W_sa^T + b_sa)  (K = 256 + 288)
    {
      GD d = z;
      d.A1 = sprev_b; d.lda1 = SD; d.K1 = SD;
      d.A2 = actme_b + (size_t)t * NB * 288; d.lda2 = 288; d.K = 544;
      d.W = Wsa_b; d.ldw = 544; d.bias = b_sa; d.Cb = hid_b; d.ldc = BD;
      gemm_p<1><<<dim3(8, 8, 1), 256, 0, stream>>>(d, d);
    }
    // 2) gi = hid @ W_ih^T + b_ih ; gh = belief @ W_hh^T + b_hh  (z-merged)
    {
      GD di = z, dh = z;
      di.A1 = hid_b; di.lda1 = BD; di.K1 = BD; di.K = BD;
      di.W = Wih_b; di.ldw = BD; di.bias = b_ih; di.Cf = gi_f; di.ldc = 3 * BD;
      dh.A1 = bel_b; dh.lda1 = BD; dh.K1 = BD; dh.K = BD;
      dh.W = Whh_b; dh.ldw = BD; dh.bias = b_hh; dh.Cf = gh_f; dh.ldc = 3 * BD;
      gemm_p<0><<<dim3(8, 24, 2), 256, 0, stream>>>(di, dh);
    }
    // 3) GRU pointwise (belief -> d_out fp32 + bel_b bf16) + obs/mp bf16 build
    gru_obs<<<(NB * 2304 + 255) / 256, 256, 0, stream>>>(gi_f, gh_f, hprev, obs_t, mp_t,
                                                         out_bel, bel_b, obsmp_b);
    // 4) hp = relu(bel @ W_bp^T) ; hq = relu([bel | obsmp] @ W_bq^T)  (z-merged)
    {
      GD dp = z, dq = z;
      dp.A1 = bel_b; dp.lda1 = BD; dp.K1 = BD; dp.K = BD;
      dp.W = Wbp_b; dp.ldw = BD; dp.bias = b_bp; dp.Cb = hp_b; dp.ldc = HD;
      dq.A1 = bel_b; dq.lda1 = BD; dq.K1 = BD;
      dq.A2 = obsmp_b; dq.lda2 = 1280; dq.K = 2304;
      dq.W = Wbq_b; dq.ldw = 2304; dq.bias = b_bq; dq.Cb = hq_b; dq.ldc = HD;
      gemm_p<1><<<dim3(8, 8, 2), 256, 0, stream>>>(dp, dq);
    }
    // 5) p/q heads: GEMM + fused softplus/state epilogue + next-step sprev carry
    {
      GD hp_ = z, hq_ = z;
      hp_.A1 = hp_b; hp_.lda1 = HD; hp_.K1 = HD; hp_.K = HD;
      hp_.W = Wsp_ro; hp_.ldw = HD; hp_.bias = bsp_ro;
      hp_.noise = np_t;
      hp_.st_o = out + o_ps + (size_t)t * NB * SD;
      hp_.mn_o = out + o_ps + blk + (size_t)t * NB * SD;
      hp_.sd_o = out + o_ps + 2 * blk + (size_t)t * NB * SD;
      hp_.ntn = ntn; hp_.sprev = sprev_b; hp_.isq = 0;
      hq_.A1 = hq_b; hq_.lda1 = HD; hq_.K1 = HD; hq_.K = HD;
      hq_.W = Wsq_ro; hq_.ldw = HD; hq_.bias = bsq_ro;
      hq_.noise = nq_t;
      hq_.st_o = out + o_ps + 3 * blk + (size_t)t * NB * SD;
      hq_.mn_o = out + o_ps + 4 * blk + (size_t)t * NB * SD;
      hq_.sd_o = out + o_ps + 5 * blk + (size_t)t * NB * SD;
      hq_.ntn = ntn; hq_.sprev = sprev_b; hq_.isq = 1;
      gemm_p<2><<<dim3(8, 4, 2), 256, 0, stream>>>(hp_, hq_);
    }
  }
}